// Round 7
// baseline (36728.461 us; speedup 1.0000x reference)
//
#include <hip/hip_runtime.h>
#include <hip/hip_cooperative_groups.h>
#include <cmath>

// ResLSTM+CRF on MI355X, fp32 vector-ALU implementation.
// R13 = R12 with k4's 513 per-step dispatches collapsed into ONE persistent
// cooperative kernel (hipLaunchCooperativeKernel) using grid.sync() between
// super-steps. Step body is byte-identical to R12's proven k4s math, with
// ordinary loads/stores only — cross-block ordering comes from the runtime's
// grid barrier (architecturally supported), NOT the abandoned homemade
// relaxed-atomic protocol. c-state returns to registers (thread-local).
// k0/k2/k4b/k5 unchanged from R12 (k2 keeps its proven persistent protocol).

namespace cg = cooperative_groups;

namespace {
constexpr int SS = 512;     // seq len
constexpr int BB = 64;      // batch
constexpr int EE = 256;     // embed dim
constexpr int HHd = 256;    // half hidden (bi-lstm)
constexpr int HD = 512;     // hidden (stack)
constexpr int NTAG = 22;
constexpr int TSTART = 20;
constexpr int TSTOP = 21;

// ws offsets (in floats) — IDENTICAL footprint to the proven layout.
constexpr size_t OFF_BI    = 0;                                      // [512][512][64] chunked
constexpr size_t OFF_H1H   = OFF_BI    + (size_t)SS * HD * BB;       // [513][512][64] chunked
constexpr size_t OFF_XT    = OFF_H1H   + (size_t)(SS + 1) * HD * BB; // [512][256][64]
constexpr size_t OFF_FEATS = OFF_XT    + (size_t)SS * EE * BB;       // [512][22][64]
constexpr size_t OFF_H0R   = OFF_FEATS + (size_t)SS * NTAG * BB;     // [2][512][64] ping-pong
constexpr size_t OFF_HF    = OFF_H0R   + 2 * (size_t)HD * BB;        // [2][256][64] (k2, coherent)
constexpr size_t OFF_HB    = OFF_HF    + 2 * (size_t)HHd * BB;
constexpr size_t OFF_BAR   = OFF_HB    + 2 * (size_t)HHd * BB;       // barrier state (ints, k2 only)
constexpr int BAR_INTS = 1152;
}

__device__ __forceinline__ int cidx(int k, int lane) {
  return ((k >> 2) << 8) + (lane << 2) + (k & 3);
}

// ---- k2-only coherence helpers (proven; unchanged) ----
__device__ __forceinline__ float4 cload4(const float4* p) {
  float4 r;
  asm volatile("global_load_dwordx4 %0, %1, off sc0 sc1" : "=v"(r) : "v"(p));
  return r;
}
__device__ __forceinline__ void vwait0() {
  asm volatile("s_waitcnt vmcnt(0)" ::: "memory");
}
__device__ __forceinline__ void cstore(float* p, float v) {
  __hip_atomic_store(p, v, __ATOMIC_RELAXED, __HIP_MEMORY_SCOPE_AGENT);
}

// Centralized-release device barrier (k2 only), no fences.
template <int NBLK>
__device__ __forceinline__ void gbarC(int* flags, int* release, int bid, int epoch) {
  __syncthreads();
  if (threadIdx.x == 0) {
    __hip_atomic_store(flags + bid, epoch + 1, __ATOMIC_RELAXED, __HIP_MEMORY_SCOPE_AGENT);
  }
  if (bid == 0) {
    if (threadIdx.x < 64) {
      constexpr int PER = NBLK / 64;
      bool ok;
      do {
        ok = true;
#pragma unroll
        for (int i = 0; i < PER; ++i) {
          ok = ok && (__hip_atomic_load(flags + threadIdx.x * PER + i, __ATOMIC_RELAXED,
                                        __HIP_MEMORY_SCOPE_AGENT) > epoch);
        }
      } while (__any(!ok));
      if (threadIdx.x == 0) {
        __hip_atomic_store(release, epoch + 1, __ATOMIC_RELAXED, __HIP_MEMORY_SCOPE_AGENT);
      }
    }
  } else {
    if (threadIdx.x == 0) {
      while (__hip_atomic_load(release, __ATOMIC_RELAXED, __HIP_MEMORY_SCOPE_AGENT) <= epoch) {
        __builtin_amdgcn_s_sleep(1);
      }
    }
  }
  __syncthreads();
}

__device__ __forceinline__ float sigm(float x) { return 1.f / (1.f + expf(-x)); }
__device__ __forceinline__ float comp4(float4 v, int w) {
  return (w == 0) ? v.x : (w == 1) ? v.y : (w == 2) ? v.z : v.w;
}

// K0: gather embeddings, transpose to chunked [t][e-chunk][lane][4]
__global__ __launch_bounds__(256) void k0(const int* __restrict__ sent,
                                          const float* __restrict__ emb,
                                          float* __restrict__ xT) {
  const int t = blockIdx.x;
  const int lane = threadIdx.x & 63;
  const int w = __builtin_amdgcn_readfirstlane(threadIdx.x >> 6); // 0..3
  __shared__ float tile[64][65];
  __shared__ int rows[64];
  if (threadIdx.x < 64) rows[threadIdx.x] = sent[(size_t)threadIdx.x * SS + t];
  __syncthreads();
  float4* xT4 = (float4*)xT;
  for (int e0 = 0; e0 < EE; e0 += 64) {
    for (int bb = 0; bb < 16; ++bb) {
      int b = bb * 4 + w;
      tile[b][lane] = emb[(size_t)rows[b] * EE + e0 + lane];
    }
    __syncthreads();
    for (int r = 0; r < 4; ++r) {
      int ecl = w * 4 + r;
      int ec = (e0 >> 2) + ecl;
      float4 v = make_float4(tile[lane][ecl * 4 + 0], tile[lane][ecl * 4 + 1],
                             tile[lane][ecl * 4 + 2], tile[lane][ecl * 4 + 3]);
      xT4[((size_t)t * 64 + ec) * 64 + lane] = v;
    }
    __syncthreads();
  }
}

struct K2A {
  const float* xT; float* bi;
  const float* wih_f; const float* whh_f; const float* b_f;
  const float* wih_b; const float* whh_b; const float* b_b;
  const float* h10; const float* c10; const int* lengths;
  float* hf; float* hb;
  int* bar;
};

// K2: BiLSTM. 256 blocks x 512 thr (1 block/CU). PROVEN structure, unchanged.
__global__ __launch_bounds__(512) void k2(K2A a) {
  const int lane = threadIdx.x & 63;
  const int w = __builtin_amdgcn_readfirstlane((int)threadIdx.x >> 6); // 0..7
  const int d = (int)blockIdx.x >> 7;
  const int lb = (int)blockIdx.x & 127;
  int* flags = a.bar + d * 384;
  int* release = a.bar + d * 384 + 160;
  const int u0 = lb * 2;
  const float* wih = d ? a.wih_b : a.wih_f;
  const float* whh = d ? a.whh_b : a.whh_f;
  const float* bias = d ? a.b_b : a.b_f;
  float* hbuf = d ? a.hb : a.hf;

  __shared__ float lw[8 * 512];          // 16 KB: [r][z-k], r = g*2+ul
  __shared__ float4 part[8][2][64];      // 16 KB

#pragma unroll
  for (int i = 0; i < 2; ++i) {
    int f4 = i * 512 + (int)threadIdx.x; // 0..1023
    int r = f4 >> 7;                     // 128 f4 per row
    int kk = (f4 & 127) * 4;
    int g = r >> 1, ul = r & 1;
    int grow = g * HHd + u0 + ul;
    float4 v = (kk < 256) ? *(const float4*)(wih + (size_t)grow * 256 + kk)
                          : *(const float4*)(whh + (size_t)grow * 256 + (kk - 256));
    *(float4*)(lw + r * 512 + kk) = v;
  }

  const int len = a.lengths[lane];
  float c_st = 0.f, h_old = 0.f;
  if (w < 2) {
    int u = u0 + w;
    h_old = a.h10[d * 256 + u];
    c_st = a.c10[d * 256 + u];
    cstore(&hbuf[cidx(u, lane)], h_old);
    vwait0();
  }
  int ep = 0;
  gbarC<128>(flags, release, lb, ep); ep++;   // entry __syncthreads orders staging

  const int ks = w * 64;                 // z-slice start (0..448)
  const bool hpart = (w >= 4);
  const float4* lw4 = (const float4*)lw;
  int buf = 0;
  for (int step = 0; step < SS; ++step) {
    const int t = d ? (SS - 1 - step) : step;
    const float* actbase = hpart ? (hbuf + (size_t)buf * (HHd * 64))
                                 : (a.xT + (size_t)t * (EE * 64));
    const int ksl = hpart ? (ks - 256) : ks;
    const float4* p = (const float4*)actbase + (size_t)(ksl >> 2) * 64 + lane;
    float4 va[16];
    if (hpart) {
#pragma unroll
      for (int c = 0; c < 16; ++c) va[c] = cload4(p + (size_t)c * 64);
      vwait0();
    } else {
#pragma unroll
      for (int c = 0; c < 16; ++c) va[c] = p[(size_t)c * 64];
    }
    float acc[8] = {0, 0, 0, 0, 0, 0, 0, 0};
#pragma unroll
    for (int c = 0; c < 16; ++c) {
      float4 h = va[c];
#pragma unroll
      for (int r = 0; r < 8; ++r) {
        float4 wv = lw4[r * 128 + (ks >> 2) + c];   // broadcast ds_read_b128
        acc[r] = fmaf(h.x, wv.x, acc[r]);
        acc[r] = fmaf(h.y, wv.y, acc[r]);
        acc[r] = fmaf(h.z, wv.z, acc[r]);
        acc[r] = fmaf(h.w, wv.w, acc[r]);
      }
    }
    part[w][0][lane] = make_float4(acc[0], acc[1], acc[2], acc[3]);
    part[w][1][lane] = make_float4(acc[4], acc[5], acc[6], acc[7]);
    __syncthreads();
    if (w < 2) {
      float qi = 0.f, qf = 0.f, qg = 0.f, qo = 0.f;
#pragma unroll
      for (int wv = 0; wv < 8; ++wv) {
        float4 p0 = part[wv][0][lane], p1 = part[wv][1][lane];
        qi += comp4(p0, w);  qf += comp4(p0, 2 + w);
        qg += comp4(p1, w);  qo += comp4(p1, 2 + w);
      }
      const int u = u0 + w;
      float gi = qi + bias[u];
      float gf = qf + bias[256 + u];
      float gg = qg + bias[512 + u];
      float go = qo + bias[768 + u];
      float i_ = sigm(gi), f_ = sigm(gf), o_ = sigm(go);
      float gn = tanhf(gg);
      float c2 = f_ * c_st + i_ * gn;
      float h2 = o_ * tanhf(c2);
      const bool m = (t < len);
      h2 = m ? h2 : h_old;
      c_st = m ? c2 : c_st;
      h_old = h2;
      cstore(&hbuf[(size_t)(buf ^ 1) * (HHd * 64) + cidx(u, lane)], h2);
      a.bi[(size_t)t * (HD * 64) + cidx(d * 256 + u, lane)] = m ? h2 : 0.f;
      vwait0();
    }
    buf ^= 1;
    gbarC<128>(flags, release, lb, ep); ep++;
  }
}

// K4i: seed h0r slot0 and h1h slot0 from h20 (re-run every call; ws poisoned).
__global__ __launch_bounds__(512) void k4i(const float* __restrict__ h20,
                                           float* __restrict__ h0r,
                                           float* __restrict__ h1h) {
  const int layer = blockIdx.x;          // 0..1
  const int u = threadIdx.x;             // 0..511
  const float hv = h20[layer * 512 + u];
  float* hd = layer ? h1h : h0r;
#pragma unroll 4
  for (int lane = 0; lane < 64; ++lane) {
    hd[cidx(u, lane)] = hv;
  }
}

struct K4S {
  const float* bi; float* h0r; float* h1h;
  const float* wihs; const float* whhs; const float* bs;
  const float* h20; const float* c20;
};

// K4c: persistent cooperative 2-layer stack LSTM. 256 blocks x 512 thr
// (1 block/CU). Block (layer = bid>>7, lb) owns units 4lb..4lb+3 (16 gate rows
// r = g*4+ul). Waves 0-3: x-half (wih) 128-k slices; waves 4-7: h-half (whh).
// Per super-step t: layer0 computes step t, layer1 computes step t-1 (software
// pipeline), then grid.sync(). All data via ordinary loads/stores — the grid
// barrier provides device-scope ordering. Step math identical to R12's k4s.
__global__ __launch_bounds__(512) void k4c(K4S a) {
  cg::grid_group grid = cg::this_grid();
  const int lane = threadIdx.x & 63;
  const int w = __builtin_amdgcn_readfirstlane((int)threadIdx.x >> 6);  // 0..7
  const int layer = (int)blockIdx.x >> 7;
  const int lb = (int)blockIdx.x & 127;
  const int u0 = lb * 4;
  const float* wih = a.wihs + (size_t)layer * (2048 * 512);
  const float* whh = a.whhs + (size_t)layer * (2048 * 512);

  __shared__ float part[4][16][64];      // 16 KB

  const int ks = (w & 3) * 128;
  const bool hpart = (w >= 4);
  const float* wsel = hpart ? whh : wih;
  const float* wr[16];
#pragma unroll
  for (int g = 0; g < 4; ++g)
#pragma unroll
    for (int ul = 0; ul < 4; ++ul)
      wr[g * 4 + ul] = wsel + (size_t)(g * HD + u0 + ul) * HD + ks;

  // c-state in registers (w<4 threads own unit u0+w across all lanes' batch col)
  float c_st = 0.f;
  if (w < 4) c_st = a.c20[layer * 512 + u0 + w];
  const float* bsl = a.bs + (size_t)layer * 2048;

  for (int t = 0; t <= SS; ++t) {
    const bool active = (layer == 0) ? (t < SS) : (t >= 1);
    float acc[16] = {0, 0, 0, 0, 0, 0, 0, 0, 0, 0, 0, 0, 0, 0, 0, 0};
    if (active) {
      const float* actbase;
      if (layer == 0)
        actbase = hpart ? (a.h0r + (size_t)(t & 1) * (HD * 64))
                        : (a.bi + (size_t)t * (HD * 64));
      else
        actbase = hpart ? (a.h1h + (size_t)(t - 1) * (HD * 64))
                        : (a.h0r + (size_t)(t & 1) * (HD * 64));
      const float4* p = (const float4*)actbase + (size_t)(ks >> 2) * 64 + lane;
#pragma unroll
      for (int gseg = 0; gseg < 2; ++gseg) {
        float4 va[16];
        const float4* pg = p + (size_t)gseg * 16 * 64;
#pragma unroll
        for (int c = 0; c < 16; ++c) va[c] = pg[(size_t)c * 64];
#pragma unroll
        for (int c = 0; c < 16; ++c) {
          float4 h = va[c];
          const int k = (gseg * 16 + c) * 4;
#pragma unroll
          for (int r = 0; r < 16; ++r) {
            float4 wv = *(const float4*)(wr[r] + k);      // cached global
            acc[r] = fmaf(h.x, wv.x, acc[r]);
            acc[r] = fmaf(h.y, wv.y, acc[r]);
            acc[r] = fmaf(h.z, wv.z, acc[r]);
            acc[r] = fmaf(h.w, wv.w, acc[r]);
          }
        }
      }
    }
    // 2-stage cross-wave reduction: waves 0-3 write, waves 4-7 add.
    if (w < 4) {
#pragma unroll
      for (int r = 0; r < 16; ++r) part[w][r][lane] = acc[r];
    }
    __syncthreads();
    if (w >= 4) {
#pragma unroll
      for (int r = 0; r < 16; ++r) part[w - 4][r][lane] += acc[r];
    }
    __syncthreads();
    if (active && w < 4) {
      float q[4];
#pragma unroll
      for (int g = 0; g < 4; ++g) {
        float s = 0.f;
#pragma unroll
        for (int sl = 0; sl < 4; ++sl) s += part[sl][g * 4 + w][lane];
        q[g] = s;
      }
      const int u = u0 + w;
      float gi = q[0] + bsl[u];
      float gf = q[1] + bsl[512 + u];
      float gg = q[2] + bsl[1024 + u];
      float go = q[3] + bsl[1536 + u];
      float i_ = sigm(gi), f_ = sigm(gf), o_ = sigm(go);
      float gn = tanhf(gg);
      float c2 = f_ * c_st + i_ * gn;
      float h2 = o_ * tanhf(c2);
      c_st = c2;
      if (layer == 0)
        a.h0r[(size_t)((t + 1) & 1) * (HD * 64) + cidx(u, lane)] = h2;
      else
        a.h1h[(size_t)t * (HD * 64) + cidx(u, lane)] = h2;
    }
    grid.sync();
  }
}

// K4b: feats[t][j][b] = h1(t) . W_tag[j] + b_tag[j]
__global__ __launch_bounds__(256) void k4b(const float* __restrict__ h1h,
                                           const float* __restrict__ Wtag,
                                           const float* __restrict__ btag,
                                           float* __restrict__ feats) {
  const int t = blockIdx.x;
  const int lane = threadIdx.x & 63;
  const int w = __builtin_amdgcn_readfirstlane(threadIdx.x >> 6);
  const int j0 = w * 6;
  const float4* p = (const float4*)(h1h + (size_t)(t + 1) * (HD * 64)) + lane;
  const float* r[6];
  float acc[6];
#pragma unroll
  for (int jj = 0; jj < 6; ++jj) {
    int j = j0 + jj; if (j > 21) j = 21;
    r[jj] = Wtag + (size_t)j * HD;
    acc[jj] = btag[j];
  }
#pragma unroll 2
  for (int c = 0; c < 128; ++c) {
    float4 h = p[(size_t)c * 64];
    int k = c * 4;
#pragma unroll
    for (int jj = 0; jj < 6; ++jj) {
      acc[jj] = fmaf(h.x, r[jj][k], acc[jj]);
      acc[jj] = fmaf(h.y, r[jj][k + 1], acc[jj]);
      acc[jj] = fmaf(h.z, r[jj][k + 2], acc[jj]);
      acc[jj] = fmaf(h.w, r[jj][k + 3], acc[jj]);
    }
  }
#pragma unroll
  for (int jj = 0; jj < 6; ++jj) {
    int j = j0 + jj;
    if (j < NTAG) feats[((size_t)t * NTAG + j) * 64 + lane] = acc[jj];
  }
}

// K5: Viterbi decode, one block per batch element, backpointers in LDS.
__global__ __launch_bounds__(64) void k5(const float* __restrict__ feats,
                                         const float* __restrict__ trans,
                                         const int* __restrict__ lengths,
                                         float* __restrict__ out) {
  const int b = blockIdx.x;
  const int j = threadIdx.x;
  __shared__ float tr[NTAG * NTAG];
  __shared__ float sc[NTAG];
  __shared__ float term[NTAG];
  __shared__ unsigned char bp[SS - 1][NTAG];
  for (int i = j; i < NTAG * NTAG; i += 64) tr[i] = trans[i];
  const int len = lengths[b];
  float score = 0.f;
  __syncthreads();
  if (j < NTAG) {
    score = feats[(size_t)j * 64 + b] + tr[j * NTAG + TSTART];
    sc[j] = score;
  }
  __syncthreads();
  for (int t = 1; t < len; ++t) {
    float best = -3.4e38f; int bi_ = 0;
    if (j < NTAG) {
#pragma unroll
      for (int i = 0; i < NTAG; ++i) {
        float c = sc[i] + tr[j * NTAG + i];
        if (c > best) { best = c; bi_ = i; }   // strict > keeps first max
      }
      score = best + feats[((size_t)t * NTAG + j) * 64 + b];
      bp[t - 1][j] = (unsigned char)bi_;
    }
    __syncthreads();
    if (j < NTAG) sc[j] = score;
    __syncthreads();
  }
  if (j < NTAG) term[j] = score + tr[TSTOP * NTAG + j];
  __syncthreads();
  if (j == 0) {
    float bs = term[0]; int bt = 0;
    for (int i = 1; i < NTAG; ++i) if (term[i] > bs) { bs = term[i]; bt = i; }
    out[b] = bs;
    int tag = bt;
    for (int t = SS - 1; t >= 1; --t) {
      out[64 + (size_t)b * SS + t] = (float)tag;
      if (t < len) tag = bp[t - 1][tag];
    }
    out[64 + (size_t)b * SS + 0] = (float)tag;
  }
}

extern "C" void kernel_launch(void* const* d_in, const int* in_sizes, int n_in,
                              void* d_out, int out_size, void* d_ws, size_t ws_size,
                              hipStream_t stream) {
  const int* sentence = (const int*)d_in[0];
  const int* lengths  = (const int*)d_in[1];
  const float* emb    = (const float*)d_in[2];
  const float* wih_f  = (const float*)d_in[3];
  const float* whh_f  = (const float*)d_in[4];
  const float* b_f    = (const float*)d_in[5];
  const float* wih_b  = (const float*)d_in[6];
  const float* whh_b  = (const float*)d_in[7];
  const float* b_b    = (const float*)d_in[8];
  const float* h10    = (const float*)d_in[9];
  const float* c10    = (const float*)d_in[10];
  const float* wihs   = (const float*)d_in[11];
  const float* whhs   = (const float*)d_in[12];
  const float* bs     = (const float*)d_in[13];
  const float* h20    = (const float*)d_in[14];
  const float* c20    = (const float*)d_in[15];
  const float* Wtag   = (const float*)d_in[16];
  const float* btag   = (const float*)d_in[17];
  const float* trans  = (const float*)d_in[18];
  float* ws = (float*)d_ws;
  float* out = (float*)d_out;
  int* barbase = (int*)(ws + OFF_BAR);

  // zero barrier state (ws is poisoned 0xAA before every call) — k2 only
  hipMemsetAsync((void*)barbase, 0, BAR_INTS * sizeof(int), stream);

  k0<<<dim3(SS), dim3(256), 0, stream>>>(sentence, emb, ws + OFF_XT);

  K2A a2{ws + OFF_XT, ws + OFF_BI, wih_f, whh_f, b_f, wih_b, whh_b, b_b,
         h10, c10, lengths,
         ws + OFF_HF, ws + OFF_HB,
         barbase};
  k2<<<dim3(256), dim3(512), 0, stream>>>(a2);

  // k4: seed h-state, then ONE cooperative persistent kernel (513 grid.sync's).
  k4i<<<dim3(2), dim3(512), 0, stream>>>(h20, ws + OFF_H0R, ws + OFF_H1H);
  K4S a4{ws + OFF_BI, ws + OFF_H0R, ws + OFF_H1H, wihs, whhs, bs, h20, c20};
  void* kargs[] = { (void*)&a4 };
  hipLaunchCooperativeKernel((void*)k4c, dim3(256), dim3(512), kargs, 0, stream);

  k4b<<<dim3(SS), dim3(256), 0, stream>>>(ws + OFF_H1H, Wtag, btag, ws + OFF_FEATS);
  k5<<<dim3(BB), dim3(64), 0, stream>>>(ws + OFF_FEATS, trans, lengths, out);
}

// Round 8
// 11196.021 us; speedup vs baseline: 3.2805x; 3.2805x over previous
//
#include <hip/hip_runtime.h>
#include <cmath>

// ResLSTM+CRF on MI355X, fp32 vector-ALU implementation.
// R14 = R12 (proven 12661 us: k4 as one dispatch per super-step, ordinary
// loads/stores, stream-ordered) with ONE delta:
//   k4s: 1024 threads/block (16 waves/CU, 4/SIMD — 2x latency-hiding TLP).
//   z=1024 split into 16 waves x 64-k slices (w<8: x-half via wih, w>=8:
//   h-half via whh); single 16xfloat4 activation batch per wave; 2-stage
//   part[8][16][64] LDS reduction. Per-unit math identical to R12.
// R13's cooperative grid.sync() cost ~60us/sync (32 ms total) — abandoned.
// k2 keeps the R11-proven persistent structure + gbarC protocol unchanged.

namespace {
constexpr int SS = 512;     // seq len
constexpr int BB = 64;      // batch
constexpr int EE = 256;     // embed dim
constexpr int HHd = 256;    // half hidden (bi-lstm)
constexpr int HD = 512;     // hidden (stack)
constexpr int NTAG = 22;
constexpr int TSTART = 20;
constexpr int TSTOP = 21;

// ws offsets (in floats) — IDENTICAL footprint to the proven layout.
constexpr size_t OFF_BI    = 0;                                      // [512][512][64] chunked
constexpr size_t OFF_H1H   = OFF_BI    + (size_t)SS * HD * BB;       // [513][512][64] chunked
constexpr size_t OFF_XT    = OFF_H1H   + (size_t)(SS + 1) * HD * BB; // [512][256][64]; dead after k2 -> k4 c-state
constexpr size_t OFF_FEATS = OFF_XT    + (size_t)SS * EE * BB;       // [512][22][64]
constexpr size_t OFF_H0R   = OFF_FEATS + (size_t)SS * NTAG * BB;     // [2][512][64] ping-pong
constexpr size_t OFF_HF    = OFF_H0R   + 2 * (size_t)HD * BB;        // [2][256][64] (k2, coherent)
constexpr size_t OFF_HB    = OFF_HF    + 2 * (size_t)HHd * BB;
constexpr size_t OFF_BAR   = OFF_HB    + 2 * (size_t)HHd * BB;       // barrier state (ints, k2 only)
constexpr int BAR_INTS = 1152;

// k4 c-state, carved from the dead xT region
constexpr size_t OFF_C0 = OFF_XT;                    // [512][64] chunked (cidx)
constexpr size_t OFF_C1 = OFF_XT + (size_t)HD * BB;  // [512][64] chunked
}

__device__ __forceinline__ int cidx(int k, int lane) {
  return ((k >> 2) << 8) + (lane << 2) + (k & 3);
}

// ---- k2-only coherence helpers (proven; unchanged) ----
__device__ __forceinline__ float4 cload4(const float4* p) {
  float4 r;
  asm volatile("global_load_dwordx4 %0, %1, off sc0 sc1" : "=v"(r) : "v"(p));
  return r;
}
__device__ __forceinline__ void vwait0() {
  asm volatile("s_waitcnt vmcnt(0)" ::: "memory");
}
__device__ __forceinline__ void cstore(float* p, float v) {
  __hip_atomic_store(p, v, __ATOMIC_RELAXED, __HIP_MEMORY_SCOPE_AGENT);
}

// Centralized-release device barrier (k2 only), no fences.
template <int NBLK>
__device__ __forceinline__ void gbarC(int* flags, int* release, int bid, int epoch) {
  __syncthreads();
  if (threadIdx.x == 0) {
    __hip_atomic_store(flags + bid, epoch + 1, __ATOMIC_RELAXED, __HIP_MEMORY_SCOPE_AGENT);
  }
  if (bid == 0) {
    if (threadIdx.x < 64) {
      constexpr int PER = NBLK / 64;
      bool ok;
      do {
        ok = true;
#pragma unroll
        for (int i = 0; i < PER; ++i) {
          ok = ok && (__hip_atomic_load(flags + threadIdx.x * PER + i, __ATOMIC_RELAXED,
                                        __HIP_MEMORY_SCOPE_AGENT) > epoch);
        }
      } while (__any(!ok));
      if (threadIdx.x == 0) {
        __hip_atomic_store(release, epoch + 1, __ATOMIC_RELAXED, __HIP_MEMORY_SCOPE_AGENT);
      }
    }
  } else {
    if (threadIdx.x == 0) {
      while (__hip_atomic_load(release, __ATOMIC_RELAXED, __HIP_MEMORY_SCOPE_AGENT) <= epoch) {
        __builtin_amdgcn_s_sleep(1);
      }
    }
  }
  __syncthreads();
}

__device__ __forceinline__ float sigm(float x) { return 1.f / (1.f + expf(-x)); }
__device__ __forceinline__ float comp4(float4 v, int w) {
  return (w == 0) ? v.x : (w == 1) ? v.y : (w == 2) ? v.z : v.w;
}

// K0: gather embeddings, transpose to chunked [t][e-chunk][lane][4]
__global__ __launch_bounds__(256) void k0(const int* __restrict__ sent,
                                          const float* __restrict__ emb,
                                          float* __restrict__ xT) {
  const int t = blockIdx.x;
  const int lane = threadIdx.x & 63;
  const int w = __builtin_amdgcn_readfirstlane(threadIdx.x >> 6); // 0..3
  __shared__ float tile[64][65];
  __shared__ int rows[64];
  if (threadIdx.x < 64) rows[threadIdx.x] = sent[(size_t)threadIdx.x * SS + t];
  __syncthreads();
  float4* xT4 = (float4*)xT;
  for (int e0 = 0; e0 < EE; e0 += 64) {
    for (int bb = 0; bb < 16; ++bb) {
      int b = bb * 4 + w;
      tile[b][lane] = emb[(size_t)rows[b] * EE + e0 + lane];
    }
    __syncthreads();
    for (int r = 0; r < 4; ++r) {
      int ecl = w * 4 + r;
      int ec = (e0 >> 2) + ecl;
      float4 v = make_float4(tile[lane][ecl * 4 + 0], tile[lane][ecl * 4 + 1],
                             tile[lane][ecl * 4 + 2], tile[lane][ecl * 4 + 3]);
      xT4[((size_t)t * 64 + ec) * 64 + lane] = v;
    }
    __syncthreads();
  }
}

struct K2A {
  const float* xT; float* bi;
  const float* wih_f; const float* whh_f; const float* b_f;
  const float* wih_b; const float* whh_b; const float* b_b;
  const float* h10; const float* c10; const int* lengths;
  float* hf; float* hb;
  int* bar;
};

// K2: BiLSTM. 256 blocks x 512 thr (1 block/CU). PROVEN structure, unchanged.
__global__ __launch_bounds__(512) void k2(K2A a) {
  const int lane = threadIdx.x & 63;
  const int w = __builtin_amdgcn_readfirstlane((int)threadIdx.x >> 6); // 0..7
  const int d = (int)blockIdx.x >> 7;
  const int lb = (int)blockIdx.x & 127;
  int* flags = a.bar + d * 384;
  int* release = a.bar + d * 384 + 160;
  const int u0 = lb * 2;
  const float* wih = d ? a.wih_b : a.wih_f;
  const float* whh = d ? a.whh_b : a.whh_f;
  const float* bias = d ? a.b_b : a.b_f;
  float* hbuf = d ? a.hb : a.hf;

  __shared__ float lw[8 * 512];          // 16 KB: [r][z-k], r = g*2+ul
  __shared__ float4 part[8][2][64];      // 16 KB

#pragma unroll
  for (int i = 0; i < 2; ++i) {
    int f4 = i * 512 + (int)threadIdx.x; // 0..1023
    int r = f4 >> 7;                     // 128 f4 per row
    int kk = (f4 & 127) * 4;
    int g = r >> 1, ul = r & 1;
    int grow = g * HHd + u0 + ul;
    float4 v = (kk < 256) ? *(const float4*)(wih + (size_t)grow * 256 + kk)
                          : *(const float4*)(whh + (size_t)grow * 256 + (kk - 256));
    *(float4*)(lw + r * 512 + kk) = v;
  }

  const int len = a.lengths[lane];
  float c_st = 0.f, h_old = 0.f;
  if (w < 2) {
    int u = u0 + w;
    h_old = a.h10[d * 256 + u];
    c_st = a.c10[d * 256 + u];
    cstore(&hbuf[cidx(u, lane)], h_old);
    vwait0();
  }
  int ep = 0;
  gbarC<128>(flags, release, lb, ep); ep++;   // entry __syncthreads orders staging

  const int ks = w * 64;                 // z-slice start (0..448)
  const bool hpart = (w >= 4);
  const float4* lw4 = (const float4*)lw;
  int buf = 0;
  for (int step = 0; step < SS; ++step) {
    const int t = d ? (SS - 1 - step) : step;
    const float* actbase = hpart ? (hbuf + (size_t)buf * (HHd * 64))
                                 : (a.xT + (size_t)t * (EE * 64));
    const int ksl = hpart ? (ks - 256) : ks;
    const float4* p = (const float4*)actbase + (size_t)(ksl >> 2) * 64 + lane;
    float4 va[16];
    if (hpart) {
#pragma unroll
      for (int c = 0; c < 16; ++c) va[c] = cload4(p + (size_t)c * 64);
      vwait0();
    } else {
#pragma unroll
      for (int c = 0; c < 16; ++c) va[c] = p[(size_t)c * 64];
    }
    float acc[8] = {0, 0, 0, 0, 0, 0, 0, 0};
#pragma unroll
    for (int c = 0; c < 16; ++c) {
      float4 h = va[c];
#pragma unroll
      for (int r = 0; r < 8; ++r) {
        float4 wv = lw4[r * 128 + (ks >> 2) + c];   // broadcast ds_read_b128
        acc[r] = fmaf(h.x, wv.x, acc[r]);
        acc[r] = fmaf(h.y, wv.y, acc[r]);
        acc[r] = fmaf(h.z, wv.z, acc[r]);
        acc[r] = fmaf(h.w, wv.w, acc[r]);
      }
    }
    part[w][0][lane] = make_float4(acc[0], acc[1], acc[2], acc[3]);
    part[w][1][lane] = make_float4(acc[4], acc[5], acc[6], acc[7]);
    __syncthreads();
    if (w < 2) {
      float qi = 0.f, qf = 0.f, qg = 0.f, qo = 0.f;
#pragma unroll
      for (int wv = 0; wv < 8; ++wv) {
        float4 p0 = part[wv][0][lane], p1 = part[wv][1][lane];
        qi += comp4(p0, w);  qf += comp4(p0, 2 + w);
        qg += comp4(p1, w);  qo += comp4(p1, 2 + w);
      }
      const int u = u0 + w;
      float gi = qi + bias[u];
      float gf = qf + bias[256 + u];
      float gg = qg + bias[512 + u];
      float go = qo + bias[768 + u];
      float i_ = sigm(gi), f_ = sigm(gf), o_ = sigm(go);
      float gn = tanhf(gg);
      float c2 = f_ * c_st + i_ * gn;
      float h2 = o_ * tanhf(c2);
      const bool m = (t < len);
      h2 = m ? h2 : h_old;
      c_st = m ? c2 : c_st;
      h_old = h2;
      cstore(&hbuf[(size_t)(buf ^ 1) * (HHd * 64) + cidx(u, lane)], h2);
      a.bi[(size_t)t * (HD * 64) + cidx(d * 256 + u, lane)] = m ? h2 : 0.f;
      vwait0();
    }
    buf ^= 1;
    gbarC<128>(flags, release, lb, ep); ep++;
  }
}

// K4i: seed h0r[0], h1h[0], c0, c1 from h20/c20 (re-run every call; ws poisoned).
__global__ __launch_bounds__(512) void k4i(const float* __restrict__ h20,
                                           const float* __restrict__ c20,
                                           float* __restrict__ h0r,
                                           float* __restrict__ h1h,
                                           float* __restrict__ c0,
                                           float* __restrict__ c1) {
  const int layer = blockIdx.x;          // 0..1
  const int u = threadIdx.x;             // 0..511
  const float hv = h20[layer * 512 + u];
  const float cv = c20[layer * 512 + u];
  float* hd = layer ? h1h : h0r;
  float* cd = layer ? c1 : c0;
#pragma unroll 4
  for (int lane = 0; lane < 64; ++lane) {
    hd[cidx(u, lane)] = hv;
    cd[cidx(u, lane)] = cv;
  }
}

struct K4S {
  const float* bi; float* h0r; float* h1h;
  const float* wihs; const float* whhs; const float* bs;
  float* c0; float* c1;
};

// K4s: ONE super-step. 256 blocks x 1024 thr (R14: 16 waves/CU, 4/SIMD).
// Block (layer = bid>>7, lb) owns units 4lb..4lb+3 (16 gate rows r = g*4+ul).
// 16 waves x 64-k slices: w<8 -> x-half (wih, k = w*64), w>=8 -> h-half
// (whh, k = (w-8)*64). Ordinary loads/stores; cross-step ordering from the
// dispatch boundary. Per-unit math identical to R12.
__global__ __launch_bounds__(1024, 1) void k4s(K4S a, int t) {
  const int layer = (int)blockIdx.x >> 7;
  if (layer == 0) { if (t >= SS) return; } else { if (t < 1) return; }
  const int lane = threadIdx.x & 63;
  const int w = __builtin_amdgcn_readfirstlane((int)threadIdx.x >> 6);  // 0..15
  const int lb = (int)blockIdx.x & 127;
  const int u0 = lb * 4;
  const float* wih = a.wihs + (size_t)layer * (2048 * 512);
  const float* whh = a.whhs + (size_t)layer * (2048 * 512);

  __shared__ float part[8][16][64];      // 32 KB

  const int ks = (w & 7) * 64;           // k-slice start within the 512-k half
  const bool hpart = (w >= 8);
  const float* wsel = hpart ? whh : wih;
  const float* wr[16];
#pragma unroll
  for (int g = 0; g < 4; ++g)
#pragma unroll
    for (int ul = 0; ul < 4; ++ul)
      wr[g * 4 + ul] = wsel + (size_t)(g * HD + u0 + ul) * HD + ks;

  const float* actbase;
  if (layer == 0)
    actbase = hpart ? (a.h0r + (size_t)(t & 1) * (HD * 64))
                    : (a.bi + (size_t)t * (HD * 64));
  else
    actbase = hpart ? (a.h1h + (size_t)(t - 1) * (HD * 64))
                    : (a.h0r + (size_t)(t & 1) * (HD * 64));

  // load this wave's 64-k activation slice (16 float4s)
  const float4* p = (const float4*)actbase + (size_t)(ks >> 2) * 64 + lane;
  float4 va[16];
#pragma unroll
  for (int c = 0; c < 16; ++c) va[c] = p[(size_t)c * 64];

  float acc[16] = {0, 0, 0, 0, 0, 0, 0, 0, 0, 0, 0, 0, 0, 0, 0, 0};
#pragma unroll
  for (int c = 0; c < 16; ++c) {
    float4 h = va[c];
    const int k = c * 4;
#pragma unroll
    for (int r = 0; r < 16; ++r) {
      float4 wv = *(const float4*)(wr[r] + k);      // cached global (uniform)
      acc[r] = fmaf(h.x, wv.x, acc[r]);
      acc[r] = fmaf(h.y, wv.y, acc[r]);
      acc[r] = fmaf(h.z, wv.z, acc[r]);
      acc[r] = fmaf(h.w, wv.w, acc[r]);
    }
  }
  // 2-stage cross-wave reduction: waves 0-7 write, waves 8-15 add.
  if (w < 8) {
#pragma unroll
    for (int r = 0; r < 16; ++r) part[w][r][lane] = acc[r];
  }
  __syncthreads();
  if (w >= 8) {
#pragma unroll
    for (int r = 0; r < 16; ++r) part[w - 8][r][lane] += acc[r];
  }
  __syncthreads();
  if (w < 4) {
    float q[4];
#pragma unroll
    for (int g = 0; g < 4; ++g) {
      float s = 0.f;
#pragma unroll
      for (int sl = 0; sl < 8; ++sl) s += part[sl][g * 4 + w][lane];
      q[g] = s;
    }
    const int u = u0 + w;
    const float* bsl = a.bs + (size_t)layer * 2048;
    float* cst = layer ? a.c1 : a.c0;
    float c_st = cst[cidx(u, lane)];
    float gi = q[0] + bsl[u];
    float gf = q[1] + bsl[512 + u];
    float gg = q[2] + bsl[1024 + u];
    float go = q[3] + bsl[1536 + u];
    float i_ = sigm(gi), f_ = sigm(gf), o_ = sigm(go);
    float gn = tanhf(gg);
    float c2 = f_ * c_st + i_ * gn;
    float h2 = o_ * tanhf(c2);
    cst[cidx(u, lane)] = c2;
    if (layer == 0)
      a.h0r[(size_t)((t + 1) & 1) * (HD * 64) + cidx(u, lane)] = h2;
    else
      a.h1h[(size_t)t * (HD * 64) + cidx(u, lane)] = h2;
  }
}

// K4b: feats[t][j][b] = h1(t) . W_tag[j] + b_tag[j]
__global__ __launch_bounds__(256) void k4b(const float* __restrict__ h1h,
                                           const float* __restrict__ Wtag,
                                           const float* __restrict__ btag,
                                           float* __restrict__ feats) {
  const int t = blockIdx.x;
  const int lane = threadIdx.x & 63;
  const int w = __builtin_amdgcn_readfirstlane(threadIdx.x >> 6);
  const int j0 = w * 6;
  const float4* p = (const float4*)(h1h + (size_t)(t + 1) * (HD * 64)) + lane;
  const float* r[6];
  float acc[6];
#pragma unroll
  for (int jj = 0; jj < 6; ++jj) {
    int j = j0 + jj; if (j > 21) j = 21;
    r[jj] = Wtag + (size_t)j * HD;
    acc[jj] = btag[j];
  }
#pragma unroll 2
  for (int c = 0; c < 128; ++c) {
    float4 h = p[(size_t)c * 64];
    int k = c * 4;
#pragma unroll
    for (int jj = 0; jj < 6; ++jj) {
      acc[jj] = fmaf(h.x, r[jj][k], acc[jj]);
      acc[jj] = fmaf(h.y, r[jj][k + 1], acc[jj]);
      acc[jj] = fmaf(h.z, r[jj][k + 2], acc[jj]);
      acc[jj] = fmaf(h.w, r[jj][k + 3], acc[jj]);
    }
  }
#pragma unroll
  for (int jj = 0; jj < 6; ++jj) {
    int j = j0 + jj;
    if (j < NTAG) feats[((size_t)t * NTAG + j) * 64 + lane] = acc[jj];
  }
}

// K5: Viterbi decode, one block per batch element, backpointers in LDS.
__global__ __launch_bounds__(64) void k5(const float* __restrict__ feats,
                                         const float* __restrict__ trans,
                                         const int* __restrict__ lengths,
                                         float* __restrict__ out) {
  const int b = blockIdx.x;
  const int j = threadIdx.x;
  __shared__ float tr[NTAG * NTAG];
  __shared__ float sc[NTAG];
  __shared__ float term[NTAG];
  __shared__ unsigned char bp[SS - 1][NTAG];
  for (int i = j; i < NTAG * NTAG; i += 64) tr[i] = trans[i];
  const int len = lengths[b];
  float score = 0.f;
  __syncthreads();
  if (j < NTAG) {
    score = feats[(size_t)j * 64 + b] + tr[j * NTAG + TSTART];
    sc[j] = score;
  }
  __syncthreads();
  for (int t = 1; t < len; ++t) {
    float best = -3.4e38f; int bi_ = 0;
    if (j < NTAG) {
#pragma unroll
      for (int i = 0; i < NTAG; ++i) {
        float c = sc[i] + tr[j * NTAG + i];
        if (c > best) { best = c; bi_ = i; }   // strict > keeps first max
      }
      score = best + feats[((size_t)t * NTAG + j) * 64 + b];
      bp[t - 1][j] = (unsigned char)bi_;
    }
    __syncthreads();
    if (j < NTAG) sc[j] = score;
    __syncthreads();
  }
  if (j < NTAG) term[j] = score + tr[TSTOP * NTAG + j];
  __syncthreads();
  if (j == 0) {
    float bs = term[0]; int bt = 0;
    for (int i = 1; i < NTAG; ++i) if (term[i] > bs) { bs = term[i]; bt = i; }
    out[b] = bs;
    int tag = bt;
    for (int t = SS - 1; t >= 1; --t) {
      out[64 + (size_t)b * SS + t] = (float)tag;
      if (t < len) tag = bp[t - 1][tag];
    }
    out[64 + (size_t)b * SS + 0] = (float)tag;
  }
}

extern "C" void kernel_launch(void* const* d_in, const int* in_sizes, int n_in,
                              void* d_out, int out_size, void* d_ws, size_t ws_size,
                              hipStream_t stream) {
  const int* sentence = (const int*)d_in[0];
  const int* lengths  = (const int*)d_in[1];
  const float* emb    = (const float*)d_in[2];
  const float* wih_f  = (const float*)d_in[3];
  const float* whh_f  = (const float*)d_in[4];
  const float* b_f    = (const float*)d_in[5];
  const float* wih_b  = (const float*)d_in[6];
  const float* whh_b  = (const float*)d_in[7];
  const float* b_b    = (const float*)d_in[8];
  const float* h10    = (const float*)d_in[9];
  const float* c10    = (const float*)d_in[10];
  const float* wihs   = (const float*)d_in[11];
  const float* whhs   = (const float*)d_in[12];
  const float* bs     = (const float*)d_in[13];
  const float* h20    = (const float*)d_in[14];
  const float* c20    = (const float*)d_in[15];
  const float* Wtag   = (const float*)d_in[16];
  const float* btag   = (const float*)d_in[17];
  const float* trans  = (const float*)d_in[18];
  float* ws = (float*)d_ws;
  float* out = (float*)d_out;
  int* barbase = (int*)(ws + OFF_BAR);

  // zero barrier state (ws is poisoned 0xAA before every call) — k2 only
  hipMemsetAsync((void*)barbase, 0, BAR_INTS * sizeof(int), stream);

  k0<<<dim3(SS), dim3(256), 0, stream>>>(sentence, emb, ws + OFF_XT);

  K2A a2{ws + OFF_XT, ws + OFF_BI, wih_f, whh_f, b_f, wih_b, whh_b, b_b,
         h10, c10, lengths,
         ws + OFF_HF, ws + OFF_HB,
         barbase};
  k2<<<dim3(256), dim3(512), 0, stream>>>(a2);

  // k4: init state, then one dispatch per super-step (stream-ordered).
  k4i<<<dim3(2), dim3(512), 0, stream>>>(h20, c20, ws + OFF_H0R, ws + OFF_H1H,
                                         ws + OFF_C0, ws + OFF_C1);
  K4S a4{ws + OFF_BI, ws + OFF_H0R, ws + OFF_H1H, wihs, whhs, bs,
         ws + OFF_C0, ws + OFF_C1};
  for (int t = 0; t <= SS; ++t) {
    k4s<<<dim3(256), dim3(1024), 0, stream>>>(a4, t);
  }

  k4b<<<dim3(SS), dim3(256), 0, stream>>>(ws + OFF_H1H, Wtag, btag, ws + OFF_FEATS);
  k5<<<dim3(BB), dim3(64), 0, stream>>>(ws + OFF_FEATS, trans, lengths, out);
}

// Round 9
// 10386.307 us; speedup vs baseline: 3.5362x; 1.0780x over previous
//
#include <hip/hip_runtime.h>
#include <cmath>

// ResLSTM+CRF on MI355X, fp32 vector-ALU implementation.
// R15 = R14 (proven 11196 us) + two deltas:
//  1. k2 widened 512 -> 1024 threads (16 waves, 4/SIMD: 2x latency-hiding TLP,
//     per-wave z-slice 64 -> 32 k). gbarC protocol, flags layout, cload4/cstore/
//     vwait0 discipline, epilogue waves, hbuf ring: byte-identical. Only the
//     compute partition widens (same trick that won R14 on k4s).
//  2. k4s: c-state global load hoisted to kernel start (hides an L3 round trip
//     that was exposed in the serial epilogue). k4s has no sync protocol.
// k4 remains one dispatch per super-step (stream-ordered, ordinary loads/stores).

namespace {
constexpr int SS = 512;     // seq len
constexpr int BB = 64;      // batch
constexpr int EE = 256;     // embed dim
constexpr int HHd = 256;    // half hidden (bi-lstm)
constexpr int HD = 512;     // hidden (stack)
constexpr int NTAG = 22;
constexpr int TSTART = 20;
constexpr int TSTOP = 21;

// ws offsets (in floats) — IDENTICAL footprint to the proven layout.
constexpr size_t OFF_BI    = 0;                                      // [512][512][64] chunked
constexpr size_t OFF_H1H   = OFF_BI    + (size_t)SS * HD * BB;       // [513][512][64] chunked
constexpr size_t OFF_XT    = OFF_H1H   + (size_t)(SS + 1) * HD * BB; // [512][256][64]; dead after k2 -> k4 c-state
constexpr size_t OFF_FEATS = OFF_XT    + (size_t)SS * EE * BB;       // [512][22][64]
constexpr size_t OFF_H0R   = OFF_FEATS + (size_t)SS * NTAG * BB;     // [2][512][64] ping-pong
constexpr size_t OFF_HF    = OFF_H0R   + 2 * (size_t)HD * BB;        // [2][256][64] (k2, coherent)
constexpr size_t OFF_HB    = OFF_HF    + 2 * (size_t)HHd * BB;
constexpr size_t OFF_BAR   = OFF_HB    + 2 * (size_t)HHd * BB;       // barrier state (ints, k2 only)
constexpr int BAR_INTS = 1152;

// k4 c-state, carved from the dead xT region
constexpr size_t OFF_C0 = OFF_XT;                    // [512][64] chunked (cidx)
constexpr size_t OFF_C1 = OFF_XT + (size_t)HD * BB;  // [512][64] chunked
}

__device__ __forceinline__ int cidx(int k, int lane) {
  return ((k >> 2) << 8) + (lane << 2) + (k & 3);
}

// ---- k2-only coherence helpers (proven; unchanged) ----
__device__ __forceinline__ float4 cload4(const float4* p) {
  float4 r;
  asm volatile("global_load_dwordx4 %0, %1, off sc0 sc1" : "=v"(r) : "v"(p));
  return r;
}
__device__ __forceinline__ void vwait0() {
  asm volatile("s_waitcnt vmcnt(0)" ::: "memory");
}
__device__ __forceinline__ void cstore(float* p, float v) {
  __hip_atomic_store(p, v, __ATOMIC_RELAXED, __HIP_MEMORY_SCOPE_AGENT);
}

// Centralized-release device barrier (k2 only), no fences.
template <int NBLK>
__device__ __forceinline__ void gbarC(int* flags, int* release, int bid, int epoch) {
  __syncthreads();
  if (threadIdx.x == 0) {
    __hip_atomic_store(flags + bid, epoch + 1, __ATOMIC_RELAXED, __HIP_MEMORY_SCOPE_AGENT);
  }
  if (bid == 0) {
    if (threadIdx.x < 64) {
      constexpr int PER = NBLK / 64;
      bool ok;
      do {
        ok = true;
#pragma unroll
        for (int i = 0; i < PER; ++i) {
          ok = ok && (__hip_atomic_load(flags + threadIdx.x * PER + i, __ATOMIC_RELAXED,
                                        __HIP_MEMORY_SCOPE_AGENT) > epoch);
        }
      } while (__any(!ok));
      if (threadIdx.x == 0) {
        __hip_atomic_store(release, epoch + 1, __ATOMIC_RELAXED, __HIP_MEMORY_SCOPE_AGENT);
      }
    }
  } else {
    if (threadIdx.x == 0) {
      while (__hip_atomic_load(release, __ATOMIC_RELAXED, __HIP_MEMORY_SCOPE_AGENT) <= epoch) {
        __builtin_amdgcn_s_sleep(1);
      }
    }
  }
  __syncthreads();
}

__device__ __forceinline__ float sigm(float x) { return 1.f / (1.f + expf(-x)); }
__device__ __forceinline__ float comp4(float4 v, int w) {
  return (w == 0) ? v.x : (w == 1) ? v.y : (w == 2) ? v.z : v.w;
}

// K0: gather embeddings, transpose to chunked [t][e-chunk][lane][4]
__global__ __launch_bounds__(256) void k0(const int* __restrict__ sent,
                                          const float* __restrict__ emb,
                                          float* __restrict__ xT) {
  const int t = blockIdx.x;
  const int lane = threadIdx.x & 63;
  const int w = __builtin_amdgcn_readfirstlane(threadIdx.x >> 6); // 0..3
  __shared__ float tile[64][65];
  __shared__ int rows[64];
  if (threadIdx.x < 64) rows[threadIdx.x] = sent[(size_t)threadIdx.x * SS + t];
  __syncthreads();
  float4* xT4 = (float4*)xT;
  for (int e0 = 0; e0 < EE; e0 += 64) {
    for (int bb = 0; bb < 16; ++bb) {
      int b = bb * 4 + w;
      tile[b][lane] = emb[(size_t)rows[b] * EE + e0 + lane];
    }
    __syncthreads();
    for (int r = 0; r < 4; ++r) {
      int ecl = w * 4 + r;
      int ec = (e0 >> 2) + ecl;
      float4 v = make_float4(tile[lane][ecl * 4 + 0], tile[lane][ecl * 4 + 1],
                             tile[lane][ecl * 4 + 2], tile[lane][ecl * 4 + 3]);
      xT4[((size_t)t * 64 + ec) * 64 + lane] = v;
    }
    __syncthreads();
  }
}

struct K2A {
  const float* xT; float* bi;
  const float* wih_f; const float* whh_f; const float* b_f;
  const float* wih_b; const float* whh_b; const float* b_b;
  const float* h10; const float* c10; const int* lengths;
  float* hf; float* hb;
  int* bar;
};

// K2: BiLSTM. 256 blocks x 1024 thr (R15: 16 waves, 4/SIMD). Block (d, lb)
// owns units {2lb, 2lb+1} (8 gate rows, r = g*2+ul). Weights (8x512 z) in LDS.
// 16 waves x 32-k slices: w<8 -> x (xT, ordinary), w>=8 -> h (hbuf ring,
// coherent). Protocol (gbarC/cload4/cstore/vwait0, epilogue on waves 0-1,
// hbuf ring) byte-identical to the proven structure.
__global__ __launch_bounds__(1024, 1) void k2(K2A a) {
  const int lane = threadIdx.x & 63;
  const int w = __builtin_amdgcn_readfirstlane((int)threadIdx.x >> 6); // 0..15
  const int d = (int)blockIdx.x >> 7;
  const int lb = (int)blockIdx.x & 127;
  int* flags = a.bar + d * 384;
  int* release = a.bar + d * 384 + 160;
  const int u0 = lb * 2;
  const float* wih = d ? a.wih_b : a.wih_f;
  const float* whh = d ? a.whh_b : a.whh_f;
  const float* bias = d ? a.b_b : a.b_f;
  float* hbuf = d ? a.hb : a.hf;

  __shared__ float lw[8 * 512];          // 16 KB: [r][z-k], r = g*2+ul
  __shared__ float4 part[16][2][64];     // 32 KB

  // stage weights: 1024 float4s, 1 per thread
  {
    int f4 = (int)threadIdx.x;           // 0..1023
    int r = f4 >> 7;                     // 128 f4 per row
    int kk = (f4 & 127) * 4;
    int g = r >> 1, ul = r & 1;
    int grow = g * HHd + u0 + ul;
    float4 v = (kk < 256) ? *(const float4*)(wih + (size_t)grow * 256 + kk)
                          : *(const float4*)(whh + (size_t)grow * 256 + (kk - 256));
    *(float4*)(lw + r * 512 + kk) = v;
  }

  const int len = a.lengths[lane];
  float c_st = 0.f, h_old = 0.f;
  if (w < 2) {
    int u = u0 + w;
    h_old = a.h10[d * 256 + u];
    c_st = a.c10[d * 256 + u];
    cstore(&hbuf[cidx(u, lane)], h_old);
    vwait0();
  }
  int ep = 0;
  gbarC<128>(flags, release, lb, ep); ep++;   // entry __syncthreads orders staging

  const int ks = w * 32;                 // z-slice start (0..480)
  const bool hpart = (w >= 8);
  const float4* lw4 = (const float4*)lw;
  int buf = 0;
  for (int step = 0; step < SS; ++step) {
    const int t = d ? (SS - 1 - step) : step;
    const float* actbase = hpart ? (hbuf + (size_t)buf * (HHd * 64))
                                 : (a.xT + (size_t)t * (EE * 64));
    const int ksl = hpart ? (ks - 256) : ks;
    const float4* p = (const float4*)actbase + (size_t)(ksl >> 2) * 64 + lane;
    float4 va[8];
    if (hpart) {
#pragma unroll
      for (int c = 0; c < 8; ++c) va[c] = cload4(p + (size_t)c * 64);
      vwait0();
    } else {
#pragma unroll
      for (int c = 0; c < 8; ++c) va[c] = p[(size_t)c * 64];
    }
    float acc[8] = {0, 0, 0, 0, 0, 0, 0, 0};
#pragma unroll
    for (int c = 0; c < 8; ++c) {
      float4 h = va[c];
#pragma unroll
      for (int r = 0; r < 8; ++r) {
        float4 wv = lw4[r * 128 + (ks >> 2) + c];   // broadcast ds_read_b128
        acc[r] = fmaf(h.x, wv.x, acc[r]);
        acc[r] = fmaf(h.y, wv.y, acc[r]);
        acc[r] = fmaf(h.z, wv.z, acc[r]);
        acc[r] = fmaf(h.w, wv.w, acc[r]);
      }
    }
    part[w][0][lane] = make_float4(acc[0], acc[1], acc[2], acc[3]);
    part[w][1][lane] = make_float4(acc[4], acc[5], acc[6], acc[7]);
    __syncthreads();
    if (w < 2) {
      // acc rows: [0..3] = {i.u0,i.u1,f.u0,f.u1}, [4..7] = {g.u0,g.u1,o.u0,o.u1}
      float qi = 0.f, qf = 0.f, qg = 0.f, qo = 0.f;
#pragma unroll
      for (int wv = 0; wv < 16; ++wv) {
        float4 p0 = part[wv][0][lane], p1 = part[wv][1][lane];
        qi += comp4(p0, w);  qf += comp4(p0, 2 + w);
        qg += comp4(p1, w);  qo += comp4(p1, 2 + w);
      }
      const int u = u0 + w;
      float gi = qi + bias[u];
      float gf = qf + bias[256 + u];
      float gg = qg + bias[512 + u];
      float go = qo + bias[768 + u];
      float i_ = sigm(gi), f_ = sigm(gf), o_ = sigm(go);
      float gn = tanhf(gg);
      float c2 = f_ * c_st + i_ * gn;
      float h2 = o_ * tanhf(c2);
      const bool m = (t < len);
      h2 = m ? h2 : h_old;
      c_st = m ? c2 : c_st;
      h_old = h2;
      cstore(&hbuf[(size_t)(buf ^ 1) * (HHd * 64) + cidx(u, lane)], h2);
      a.bi[(size_t)t * (HD * 64) + cidx(d * 256 + u, lane)] = m ? h2 : 0.f;
      vwait0();
    }
    buf ^= 1;
    gbarC<128>(flags, release, lb, ep); ep++;
  }
}

// K4i: seed h0r[0], h1h[0], c0, c1 from h20/c20 (re-run every call; ws poisoned).
__global__ __launch_bounds__(512) void k4i(const float* __restrict__ h20,
                                           const float* __restrict__ c20,
                                           float* __restrict__ h0r,
                                           float* __restrict__ h1h,
                                           float* __restrict__ c0,
                                           float* __restrict__ c1) {
  const int layer = blockIdx.x;          // 0..1
  const int u = threadIdx.x;             // 0..511
  const float hv = h20[layer * 512 + u];
  const float cv = c20[layer * 512 + u];
  float* hd = layer ? h1h : h0r;
  float* cd = layer ? c1 : c0;
#pragma unroll 4
  for (int lane = 0; lane < 64; ++lane) {
    hd[cidx(u, lane)] = hv;
    cd[cidx(u, lane)] = cv;
  }
}

struct K4S {
  const float* bi; float* h0r; float* h1h;
  const float* wihs; const float* whhs; const float* bs;
  float* c0; float* c1;
};

// K4s: ONE super-step. 256 blocks x 1024 thr (16 waves/CU, 4/SIMD).
// Block (layer = bid>>7, lb) owns units 4lb..4lb+3 (16 gate rows r = g*4+ul).
// 16 waves x 64-k slices: w<8 -> x-half (wih), w>=8 -> h-half (whh).
// Ordinary loads/stores; cross-step ordering from the dispatch boundary.
// R15: c-state load hoisted to kernel start (hides L3 latency under matmul).
__global__ __launch_bounds__(1024, 1) void k4s(K4S a, int t) {
  const int layer = (int)blockIdx.x >> 7;
  if (layer == 0) { if (t >= SS) return; } else { if (t < 1) return; }
  const int lane = threadIdx.x & 63;
  const int w = __builtin_amdgcn_readfirstlane((int)threadIdx.x >> 6);  // 0..15
  const int lb = (int)blockIdx.x & 127;
  const int u0 = lb * 4;
  const float* wih = a.wihs + (size_t)layer * (2048 * 512);
  const float* whh = a.whhs + (size_t)layer * (2048 * 512);

  __shared__ float part[8][16][64];      // 32 KB

  // hoisted c-state load (consumed in the epilogue, ~matmul-length later)
  float* cst = layer ? a.c1 : a.c0;
  float c_st = 0.f;
  if (w < 4) c_st = cst[cidx(u0 + w, lane)];

  const int ks = (w & 7) * 64;           // k-slice start within the 512-k half
  const bool hpart = (w >= 8);
  const float* wsel = hpart ? whh : wih;
  const float* wr[16];
#pragma unroll
  for (int g = 0; g < 4; ++g)
#pragma unroll
    for (int ul = 0; ul < 4; ++ul)
      wr[g * 4 + ul] = wsel + (size_t)(g * HD + u0 + ul) * HD + ks;

  const float* actbase;
  if (layer == 0)
    actbase = hpart ? (a.h0r + (size_t)(t & 1) * (HD * 64))
                    : (a.bi + (size_t)t * (HD * 64));
  else
    actbase = hpart ? (a.h1h + (size_t)(t - 1) * (HD * 64))
                    : (a.h0r + (size_t)(t & 1) * (HD * 64));

  // load this wave's 64-k activation slice (16 float4s)
  const float4* p = (const float4*)actbase + (size_t)(ks >> 2) * 64 + lane;
  float4 va[16];
#pragma unroll
  for (int c = 0; c < 16; ++c) va[c] = p[(size_t)c * 64];

  float acc[16] = {0, 0, 0, 0, 0, 0, 0, 0, 0, 0, 0, 0, 0, 0, 0, 0};
#pragma unroll
  for (int c = 0; c < 16; ++c) {
    float4 h = va[c];
    const int k = c * 4;
#pragma unroll
    for (int r = 0; r < 16; ++r) {
      float4 wv = *(const float4*)(wr[r] + k);      // cached global (uniform)
      acc[r] = fmaf(h.x, wv.x, acc[r]);
      acc[r] = fmaf(h.y, wv.y, acc[r]);
      acc[r] = fmaf(h.z, wv.z, acc[r]);
      acc[r] = fmaf(h.w, wv.w, acc[r]);
    }
  }
  // 2-stage cross-wave reduction: waves 0-7 write, waves 8-15 add.
  if (w < 8) {
#pragma unroll
    for (int r = 0; r < 16; ++r) part[w][r][lane] = acc[r];
  }
  __syncthreads();
  if (w >= 8) {
#pragma unroll
    for (int r = 0; r < 16; ++r) part[w - 8][r][lane] += acc[r];
  }
  __syncthreads();
  if (w < 4) {
    float q[4];
#pragma unroll
    for (int g = 0; g < 4; ++g) {
      float s = 0.f;
#pragma unroll
      for (int sl = 0; sl < 8; ++sl) s += part[sl][g * 4 + w][lane];
      q[g] = s;
    }
    const int u = u0 + w;
    const float* bsl = a.bs + (size_t)layer * 2048;
    float gi = q[0] + bsl[u];
    float gf = q[1] + bsl[512 + u];
    float gg = q[2] + bsl[1024 + u];
    float go = q[3] + bsl[1536 + u];
    float i_ = sigm(gi), f_ = sigm(gf), o_ = sigm(go);
    float gn = tanhf(gg);
    float c2 = f_ * c_st + i_ * gn;
    float h2 = o_ * tanhf(c2);
    cst[cidx(u, lane)] = c2;
    if (layer == 0)
      a.h0r[(size_t)((t + 1) & 1) * (HD * 64) + cidx(u, lane)] = h2;
    else
      a.h1h[(size_t)t * (HD * 64) + cidx(u, lane)] = h2;
  }
}

// K4b: feats[t][j][b] = h1(t) . W_tag[j] + b_tag[j]
__global__ __launch_bounds__(256) void k4b(const float* __restrict__ h1h,
                                           const float* __restrict__ Wtag,
                                           const float* __restrict__ btag,
                                           float* __restrict__ feats) {
  const int t = blockIdx.x;
  const int lane = threadIdx.x & 63;
  const int w = __builtin_amdgcn_readfirstlane(threadIdx.x >> 6);
  const int j0 = w * 6;
  const float4* p = (const float4*)(h1h + (size_t)(t + 1) * (HD * 64)) + lane;
  const float* r[6];
  float acc[6];
#pragma unroll
  for (int jj = 0; jj < 6; ++jj) {
    int j = j0 + jj; if (j > 21) j = 21;
    r[jj] = Wtag + (size_t)j * HD;
    acc[jj] = btag[j];
  }
#pragma unroll 2
  for (int c = 0; c < 128; ++c) {
    float4 h = p[(size_t)c * 64];
    int k = c * 4;
#pragma unroll
    for (int jj = 0; jj < 6; ++jj) {
      acc[jj] = fmaf(h.x, r[jj][k], acc[jj]);
      acc[jj] = fmaf(h.y, r[jj][k + 1], acc[jj]);
      acc[jj] = fmaf(h.z, r[jj][k + 2], acc[jj]);
      acc[jj] = fmaf(h.w, r[jj][k + 3], acc[jj]);
    }
  }
#pragma unroll
  for (int jj = 0; jj < 6; ++jj) {
    int j = j0 + jj;
    if (j < NTAG) feats[((size_t)t * NTAG + j) * 64 + lane] = acc[jj];
  }
}

// K5: Viterbi decode, one block per batch element, backpointers in LDS.
__global__ __launch_bounds__(64) void k5(const float* __restrict__ feats,
                                         const float* __restrict__ trans,
                                         const int* __restrict__ lengths,
                                         float* __restrict__ out) {
  const int b = blockIdx.x;
  const int j = threadIdx.x;
  __shared__ float tr[NTAG * NTAG];
  __shared__ float sc[NTAG];
  __shared__ float term[NTAG];
  __shared__ unsigned char bp[SS - 1][NTAG];
  for (int i = j; i < NTAG * NTAG; i += 64) tr[i] = trans[i];
  const int len = lengths[b];
  float score = 0.f;
  __syncthreads();
  if (j < NTAG) {
    score = feats[(size_t)j * 64 + b] + tr[j * NTAG + TSTART];
    sc[j] = score;
  }
  __syncthreads();
  for (int t = 1; t < len; ++t) {
    float best = -3.4e38f; int bi_ = 0;
    if (j < NTAG) {
#pragma unroll
      for (int i = 0; i < NTAG; ++i) {
        float c = sc[i] + tr[j * NTAG + i];
        if (c > best) { best = c; bi_ = i; }   // strict > keeps first max
      }
      score = best + feats[((size_t)t * NTAG + j) * 64 + b];
      bp[t - 1][j] = (unsigned char)bi_;
    }
    __syncthreads();
    if (j < NTAG) sc[j] = score;
    __syncthreads();
  }
  if (j < NTAG) term[j] = score + tr[TSTOP * NTAG + j];
  __syncthreads();
  if (j == 0) {
    float bs = term[0]; int bt = 0;
    for (int i = 1; i < NTAG; ++i) if (term[i] > bs) { bs = term[i]; bt = i; }
    out[b] = bs;
    int tag = bt;
    for (int t = SS - 1; t >= 1; --t) {
      out[64 + (size_t)b * SS + t] = (float)tag;
      if (t < len) tag = bp[t - 1][tag];
    }
    out[64 + (size_t)b * SS + 0] = (float)tag;
  }
}

extern "C" void kernel_launch(void* const* d_in, const int* in_sizes, int n_in,
                              void* d_out, int out_size, void* d_ws, size_t ws_size,
                              hipStream_t stream) {
  const int* sentence = (const int*)d_in[0];
  const int* lengths  = (const int*)d_in[1];
  const float* emb    = (const float*)d_in[2];
  const float* wih_f  = (const float*)d_in[3];
  const float* whh_f  = (const float*)d_in[4];
  const float* b_f    = (const float*)d_in[5];
  const float* wih_b  = (const float*)d_in[6];
  const float* whh_b  = (const float*)d_in[7];
  const float* b_b    = (const float*)d_in[8];
  const float* h10    = (const float*)d_in[9];
  const float* c10    = (const float*)d_in[10];
  const float* wihs   = (const float*)d_in[11];
  const float* whhs   = (const float*)d_in[12];
  const float* bs     = (const float*)d_in[13];
  const float* h20    = (const float*)d_in[14];
  const float* c20    = (const float*)d_in[15];
  const float* Wtag   = (const float*)d_in[16];
  const float* btag   = (const float*)d_in[17];
  const float* trans  = (const float*)d_in[18];
  float* ws = (float*)d_ws;
  float* out = (float*)d_out;
  int* barbase = (int*)(ws + OFF_BAR);

  // zero barrier state (ws is poisoned 0xAA before every call) — k2 only
  hipMemsetAsync((void*)barbase, 0, BAR_INTS * sizeof(int), stream);

  k0<<<dim3(SS), dim3(256), 0, stream>>>(sentence, emb, ws + OFF_XT);

  K2A a2{ws + OFF_XT, ws + OFF_BI, wih_f, whh_f, b_f, wih_b, whh_b, b_b,
         h10, c10, lengths,
         ws + OFF_HF, ws + OFF_HB,
         barbase};
  k2<<<dim3(256), dim3(1024), 0, stream>>>(a2);

  // k4: init state, then one dispatch per super-step (stream-ordered).
  k4i<<<dim3(2), dim3(512), 0, stream>>>(h20, c20, ws + OFF_H0R, ws + OFF_H1H,
                                         ws + OFF_C0, ws + OFF_C1);
  K4S a4{ws + OFF_BI, ws + OFF_H0R, ws + OFF_H1H, wihs, whhs, bs,
         ws + OFF_C0, ws + OFF_C1};
  for (int t = 0; t <= SS; ++t) {
    k4s<<<dim3(256), dim3(1024), 0, stream>>>(a4, t);
  }

  k4b<<<dim3(SS), dim3(256), 0, stream>>>(ws + OFF_H1H, Wtag, btag, ws + OFF_FEATS);
  k5<<<dim3(BB), dim3(64), 0, stream>>>(ws + OFF_FEATS, trans, lengths, out);
}